// Round 1
// baseline (319.366 us; speedup 1.0000x reference)
//
#include <hip/hip_runtime.h>
#include <hip/hip_bf16.h>

#pragma clang fp contract(off)

#define B_N 32
#define A_N 32526
#define C_N 20
#define K_N 1000

// ---------------------------------------------------------------- kernel 1
// pscore[b,a] = sigmoid(max_c logits)  (sigmoid monotone => max commutes)
__global__ void k1_score(const float* __restrict__ pcls,
                         float* __restrict__ pscore, int total)
{
    int t = blockIdx.x * blockDim.x + threadIdx.x;
    if (t >= total) return;
    const float4* p = (const float4*)(pcls + (size_t)t * C_N);
    float m = -INFINITY;
#pragma unroll
    for (int q = 0; q < 5; ++q) {
        float4 v = p[q];
        m = fmaxf(m, fmaxf(fmaxf(v.x, v.y), fmaxf(v.z, v.w)));
    }
    // correctly-rounded float32 sigmoid via double
    double e = exp(-(double)m);
    pscore[t] = (float)(1.0 / (1.0 + e));
}

// ---------------------------------------------------------------- kernel 2
// per-batch exact top-K with JAX tie semantics.
// key = (float_bits(score) << 32) | (0xFFFFFFFF - idx)   (score > 0 always)
// descending key order == descending score, ties -> ascending index.
__global__ void __launch_bounds__(1024)
k2_topk(const float* __restrict__ pscore,
        int* __restrict__ topi, float* __restrict__ topv)
{
    const int b = blockIdx.x;
    const int tid = threadIdx.x;
    __shared__ unsigned int hist[256];
    __shared__ unsigned long long skey[1024];
    __shared__ unsigned long long prefix_s;
    __shared__ unsigned int kneed_s, cnt_s;

    const float* ps = pscore + (size_t)b * A_N;
    if (tid == 0) { prefix_s = 0ull; kneed_s = K_N; cnt_s = 0; }

    // radix select: find the exact K-th largest 64-bit key (keys unique)
    for (int p = 7; p >= 0; --p) {
        if (tid < 256) hist[tid] = 0;
        __syncthreads();
        const unsigned long long prefix = prefix_s;
        const int shift = p * 8;
        for (int a = tid; a < A_N; a += 1024) {
            float s = ps[a];
            unsigned long long key =
                ((unsigned long long)__float_as_uint(s) << 32) |
                (unsigned long long)(0xFFFFFFFFu - (unsigned)a);
            bool match = (p == 7) || (((key ^ prefix) >> (shift + 8)) == 0);
            if (match)
                atomicAdd(&hist[(unsigned)((key >> shift) & 0xFF)], 1u);
        }
        __syncthreads();
        if (tid == 0) {
            unsigned int cum = 0, kneed = kneed_s;
            for (int bin = 255; bin >= 0; --bin) {
                unsigned int c = hist[bin];
                if (cum + c >= kneed) {
                    kneed_s = kneed - cum;
                    prefix_s = prefix | ((unsigned long long)bin << shift);
                    break;
                }
                cum += c;
            }
        }
        __syncthreads();
    }

    // compact all keys >= kth (exactly K of them since keys are unique)
    const unsigned long long kth = prefix_s;
    for (int a = tid; a < A_N; a += 1024) {
        float s = ps[a];
        unsigned long long key =
            ((unsigned long long)__float_as_uint(s) << 32) |
            (unsigned long long)(0xFFFFFFFFu - (unsigned)a);
        if (key >= kth) {
            unsigned pos = atomicAdd(&cnt_s, 1u);
            if (pos < 1024) skey[pos] = key;
        }
    }
    __syncthreads();
    if (tid >= (int)cnt_s) skey[tid] = 0ull;   // pad to 1024
    __syncthreads();

    // bitonic sort 1024 keys, descending
    for (int k = 2; k <= 1024; k <<= 1) {
        for (int j = k >> 1; j > 0; j >>= 1) {
            int ixj = tid ^ j;
            if (ixj > tid) {
                unsigned long long a = skey[tid], b2 = skey[ixj];
                bool desc = ((tid & k) == 0);
                if (desc ? (a < b2) : (a > b2)) { skey[tid] = b2; skey[ixj] = a; }
            }
            __syncthreads();
        }
    }

    if (tid < K_N) {
        unsigned long long key = skey[tid];
        topi[(size_t)b * K_N + tid] = (int)(0xFFFFFFFFu - (unsigned)(key & 0xFFFFFFFFull));
        topv[(size_t)b * K_N + tid] = __uint_as_float((unsigned)(key >> 32));
    }
}

// ---------------------------------------------------------------- kernel 3
// decode selected boxes (ltrb), argmax label, write ids + labels outputs
__global__ void k3_decode(const float* __restrict__ ptxywh,
                          const float* __restrict__ pcls,
                          const float* __restrict__ anchors,
                          const int* __restrict__ topi,
                          float4* __restrict__ boxesws,
                          int* __restrict__ labelsws,
                          float* __restrict__ out)
{
    int t = blockIdx.x * blockDim.x + threadIdx.x;
    if (t >= B_N * K_N) return;
    int b = t / K_N;
    int a = topi[t];

    float4 tb = ((const float4*)ptxywh)[(size_t)b * A_N + a];
    float4 an = ((const float4*)anchors)[a];

    // xy = anc_xy + (t_xy*0.1)*anc_wh ; wh = anc_wh*exp(t_wh*0.2)  (np op order)
    float xx = an.x + (tb.x * 0.1f) * an.z;
    float yy = an.y + (tb.y * 0.1f) * an.w;
    float ww = an.z * (float)exp((double)(tb.z * 0.2f));
    float hh = an.w * (float)exp((double)(tb.w * 0.2f));
    float hw = ww * 0.5f, hh2 = hh * 0.5f;
    boxesws[t] = make_float4(xx - hw, yy - hh2, xx + hw, yy + hh2);

    // argmax over 20 logits (first max, like jnp.argmax)
    const float4* pc = (const float4*)(pcls + ((size_t)b * A_N + a) * C_N);
    float m = -INFINITY; int lab = 0;
#pragma unroll
    for (int q = 0; q < 5; ++q) {
        float4 v = pc[q];
        if (v.x > m) { m = v.x; lab = q * 4 + 0; }
        if (v.y > m) { m = v.y; lab = q * 4 + 1; }
        if (v.z > m) { m = v.z; lab = q * 4 + 2; }
        if (v.w > m) { m = v.w; lab = q * 4 + 3; }
    }
    labelsws[t] = lab + 1;

    out[t] = (float)b;                                 // ids_batch
    out[5 * B_N * K_N + t] = (float)(lab + 1);         // labels   (offset 160000)
}

// ---------------------------------------------------------------- kernel 4
// suppression bitmask: bit j of word w of row i  <=>  iou(i, w*64+j) > 0.5, j != i
__global__ void k4_mask(const float4* __restrict__ boxesws,
                        const int* __restrict__ labelsws,
                        unsigned long long* __restrict__ mask)
{
    const int b = blockIdx.y;
    const int tid = threadIdx.x;
    __shared__ float4 obox[K_N];
    __shared__ float oarea[K_N];

    for (int idx = tid; idx < K_N; idx += 256) {
        float4 bx = boxesws[(size_t)b * K_N + idx];
        float off = (float)labelsws[(size_t)b * K_N + idx] * 10.0f;
        float l = bx.x + off, t2 = bx.y + off, r = bx.z + off, bo = bx.w + off;
        obox[idx] = make_float4(l, t2, r, bo);
        oarea[idx] = (r - l) * (bo - t2);
    }
    __syncthreads();

    const int il = tid & 63;
    const int i = blockIdx.x * 64 + il;
    if (i >= K_N) return;
    float4 bi = obox[i];
    float ai = oarea[i];
#pragma unroll
    for (int p = 0; p < 4; ++p) {
        int w = (tid >> 6) + p * 4;
        unsigned long long word = 0ull;
        for (int jj = 0; jj < 64; ++jj) {
            int j = w * 64 + jj;
            if (j < K_N && j != i) {
                float4 bj = obox[j];
                float lx = fmaxf(bi.x, bj.x);
                float ly = fmaxf(bi.y, bj.y);
                float rx = fminf(bi.z, bj.z);
                float ry = fminf(bi.w, bj.w);
                float wx = fmaxf(rx - lx, 0.0f);
                float wy = fmaxf(ry - ly, 0.0f);
                float inter = wx * wy;
                float uni = ai + oarea[j] - inter;
                float den = fmaxf(uni, 1e-9f);
                float iou = inter / den;
                if (iou > 0.5f) word |= (1ull << jj);
            }
        }
        mask[((size_t)b * K_N + i) * 16 + w] = word;
    }
}

// ---------------------------------------------------------------- kernel 5
// greedy NMS scan (exact fori_loop semantics), one wave per batch, then outputs
__global__ void k5_scan(const unsigned long long* __restrict__ mask,
                        const float* __restrict__ topv,
                        const float4* __restrict__ boxesws,
                        float* __restrict__ out)
{
    const int b = blockIdx.x;
    const int lane = threadIdx.x;          // 64 threads = 1 wave
    __shared__ unsigned long long intrarow[64];
    __shared__ unsigned long long keeparr[16];

    const unsigned long long* mb = mask + (size_t)b * K_N * 16;
    const float* tv = topv + (size_t)b * K_N;

    unsigned long long removed[16];
#pragma unroll
    for (int w = 0; w < 16; ++w) removed[w] = 0ull;

#pragma unroll
    for (int c = 0; c < 16; ++c) {
        int row = c * 64 + lane;
        bool inr = row < K_N;
        float v = tv[inr ? row : 0];
        bool validb = inr && (v >= 0.5f);
        unsigned long long validw = __ballot(validb);

        unsigned long long iw = inr ? mb[(size_t)row * 16 + c] : 0ull;
        intrarow[lane] = iw;

        // prefetch this chunk's full mask rows, lane-distributed
        const int w = lane & 15;
        const int g = lane >> 4;
        unsigned long long mw[16];
#pragma unroll
        for (int t2 = 0; t2 < 16; ++t2) {
            int rowr = c * 64 + g * 16 + t2;
            int rc = rowr < K_N ? rowr : K_N - 1;
            mw[t2] = mb[(size_t)rc * 16 + w];
        }
        __syncthreads();

        // sequential greedy within the 64-row chunk (all lanes redundant)
        unsigned long long cw = removed[c];
        unsigned long long keepw = 0ull;
        for (int r = 0; r < 64; ++r) {
            bool kb = ((validw >> r) & 1ull) && !((cw >> r) & 1ull);
            unsigned long long sel = kb ? intrarow[r] : 0ull;
            cw |= sel;
            keepw |= (kb ? 1ull : 0ull) << r;
        }

        // union of kept rows' full mask words (deferred suppression)
        unsigned long long u = 0ull;
#pragma unroll
        for (int t2 = 0; t2 < 16; ++t2) {
            int rr = g * 16 + t2;
            bool kb = ((c * 64 + rr) < K_N) && ((keepw >> rr) & 1ull);
            u |= kb ? mw[t2] : 0ull;
        }
        u |= __shfl_xor(u, 16);
        u |= __shfl_xor(u, 32);
#pragma unroll
        for (int wq = 0; wq < 16; ++wq) removed[wq] |= __shfl(u, wq);

        if (lane == 0) keeparr[c] = keepw;
        __syncthreads();
    }

    // outputs: boxes*keep, scores*keep, keep
    float* out_boxes  = out + (size_t)B_N * K_N;          // 32000
    float* out_scores = out + (size_t)6 * B_N * K_N;      // 192000
    float* out_keep   = out + (size_t)7 * B_N * K_N;      // 224000
#pragma unroll
    for (int c = 0; c < 16; ++c) {
        int i = c * 64 + lane;
        if (i < K_N) {
            float kf = ((keeparr[c] >> lane) & 1ull) ? 1.0f : 0.0f;
            float4 bx = boxesws[(size_t)b * K_N + i];
            size_t o = (size_t)b * K_N + i;
            out_boxes[o * 4 + 0] = bx.x * kf;
            out_boxes[o * 4 + 1] = bx.y * kf;
            out_boxes[o * 4 + 2] = bx.z * kf;
            out_boxes[o * 4 + 3] = bx.w * kf;
            out_scores[o] = tv[i] * kf;
            out_keep[o] = kf;
        }
    }
}

// ---------------------------------------------------------------- launch
extern "C" void kernel_launch(void* const* d_in, const int* in_sizes, int n_in,
                              void* d_out, int out_size, void* d_ws, size_t ws_size,
                              hipStream_t stream)
{
    const float* ptxywh  = (const float*)d_in[0];
    const float* pcls    = (const float*)d_in[1];
    const float* anchors = (const float*)d_in[2];
    float* out = (float*)d_out;

    char* ws = (char*)d_ws;
    size_t o = 0;
    float* pscore = (float*)(ws + o);               o += (size_t)B_N * A_N * 4;      // 4,163,328
    int*   topi   = (int*)(ws + o);                 o += (size_t)B_N * K_N * 4;      // 128,000
    float* topv   = (float*)(ws + o);               o += (size_t)B_N * K_N * 4;
    float4* boxesws = (float4*)(ws + o);            o += (size_t)B_N * K_N * 16;     // 512,000
    int*   labelsws = (int*)(ws + o);               o += (size_t)B_N * K_N * 4;
    unsigned long long* mask = (unsigned long long*)(ws + o);
    o += (size_t)B_N * K_N * 16 * 8;                                                  // 4,096,000
    // total ws use ~9.2 MB

    int total = B_N * A_N;
    k1_score<<<(total + 255) / 256, 256, 0, stream>>>(pcls, pscore, total);
    k2_topk<<<B_N, 1024, 0, stream>>>(pscore, topi, topv);
    k3_decode<<<(B_N * K_N + 255) / 256, 256, 0, stream>>>(ptxywh, pcls, anchors,
                                                           topi, boxesws, labelsws, out);
    k4_mask<<<dim3(16, B_N), 256, 0, stream>>>(boxesws, labelsws, mask);
    k5_scan<<<B_N, 64, 0, stream>>>(mask, topv, boxesws, out);
}

// Round 2
// 206.145 us; speedup vs baseline: 1.5492x; 1.5492x over previous
//
#include <hip/hip_runtime.h>
#include <hip/hip_bf16.h>

#pragma clang fp contract(off)

#define B_N 32
#define A_N 32526
#define C_N 20
#define K_N 1000
#define NE 32   // ceil(A_N / 1024)

// ---------------------------------------------------------------- kernel 1
// pscore[b,a] = sigmoid(max_c logits)  (sigmoid monotone => max commutes)
__global__ void k1_score(const float* __restrict__ pcls,
                         float* __restrict__ pscore, int total)
{
    int t = blockIdx.x * blockDim.x + threadIdx.x;
    if (t >= total) return;
    const float4* p = (const float4*)(pcls + (size_t)t * C_N);
    float m = -INFINITY;
#pragma unroll
    for (int q = 0; q < 5; ++q) {
        float4 v = p[q];
        m = fmaxf(m, fmaxf(fmaxf(v.x, v.y), fmaxf(v.z, v.w)));
    }
    double e = exp(-(double)m);
    pscore[t] = (float)(1.0 / (1.0 + e));
}

// ---------------------------------------------------------------- kernel 2
// per-batch exact top-K, JAX tie semantics (desc value, asc index).
// Keys cached in VGPRs; MSB-descent on score bits (atomic-free block counts),
// index descent for ties, ballot compaction, bitonic sort of 1024 keys.
__global__ void __launch_bounds__(1024)
k2_topk(const float* __restrict__ pscore,
        int* __restrict__ topi, float* __restrict__ topv)
{
    const int b = blockIdx.x;
    const int tid = threadIdx.x;
    const int lane = tid & 63;
    const float* ps = pscore + (size_t)b * A_N;

    __shared__ unsigned wsum[16];
    __shared__ unsigned long long skey[1024];
    __shared__ unsigned cnt_s;

    // cache my keys (score bits; all scores in (0,1) so bits < 0x40000000)
    unsigned key[NE];
#pragma unroll
    for (int i = 0; i < NE; ++i) {
        int a = tid + i * 1024;
        key[i] = (a < A_N) ? __float_as_uint(ps[a]) : 0u;
    }

    // block-wide sum reduce, returns same value to every thread
    auto blockSum = [&](unsigned c) -> unsigned {
#pragma unroll
        for (int off = 32; off > 0; off >>= 1) c += __shfl_down(c, off);
        __syncthreads();                       // protect wsum reuse
        if (lane == 0) wsum[tid >> 6] = c;
        __syncthreads();
        unsigned t2 = 0;
#pragma unroll
        for (int w = 0; w < 16; ++w) t2 += wsum[w];
        return t2;
    };

    // MSB descent: V = exact K-th largest 32-bit score-bit value
    unsigned V = 0;
    for (int bit = 30; bit >= 0; --bit) {
        unsigned X = V | (1u << bit);
        unsigned c = 0;
#pragma unroll
        for (int i = 0; i < NE; ++i) c += (key[i] >= X) ? 1u : 0u;
        if (blockSum(c) >= K_N) V = X;
    }

    // how many strictly above; need = how many ties to take
    unsigned c0 = 0;
#pragma unroll
    for (int i = 0; i < NE; ++i) c0 += (key[i] > V) ? 1u : 0u;
    unsigned nAbove = blockSum(c0);
    unsigned need = K_N - nAbove;

    // index descent among ties: idxThr = need-th smallest tie index
    unsigned idxThr = 0;
    for (int bit = 14; bit >= 0; --bit) {
        unsigned X = idxThr | (1u << bit);
        unsigned c = 0;
#pragma unroll
        for (int i = 0; i < NE; ++i) {
            int a = tid + i * 1024;
            c += (a < A_N && key[i] == V && (unsigned)a < X) ? 1u : 0u;
        }
        if (blockSum(c) < need) idxThr = X;
    }

    // ballot compaction of exactly K_N winners
    if (tid == 0) cnt_s = 0;
    __syncthreads();
#pragma unroll
    for (int i = 0; i < NE; ++i) {
        int a = tid + i * 1024;
        bool win = (a < A_N) &&
                   (key[i] > V || (key[i] == V && (unsigned)a <= idxThr));
        unsigned long long wm = __ballot(win);
        unsigned base = 0;
        if (lane == 0 && wm) base = atomicAdd(&cnt_s, (unsigned)__popcll(wm));
        base = __shfl(base, 0);
        if (win) {
            unsigned pos = base + (unsigned)__popcll(wm & ((1ull << lane) - 1ull));
            skey[pos] = ((unsigned long long)key[i] << 32) |
                        (unsigned long long)(0xFFFFFFFFu - (unsigned)a);
        }
    }
    __syncthreads();
    if (tid >= K_N) skey[tid] = 0ull;   // pad 1000..1023
    __syncthreads();

    // bitonic sort 1024 keys, descending (keys unique: index embedded)
    for (int k = 2; k <= 1024; k <<= 1) {
        for (int j = k >> 1; j > 0; j >>= 1) {
            int ixj = tid ^ j;
            if (ixj > tid) {
                unsigned long long a2 = skey[tid], b2 = skey[ixj];
                bool desc = ((tid & k) == 0);
                if (desc ? (a2 < b2) : (a2 > b2)) { skey[tid] = b2; skey[ixj] = a2; }
            }
            __syncthreads();
        }
    }

    if (tid < K_N) {
        unsigned long long key2 = skey[tid];
        topi[(size_t)b * K_N + tid] = (int)(0xFFFFFFFFu - (unsigned)(key2 & 0xFFFFFFFFull));
        topv[(size_t)b * K_N + tid] = __uint_as_float((unsigned)(key2 >> 32));
    }
}

// ---------------------------------------------------------------- kernel 3
__global__ void k3_decode(const float* __restrict__ ptxywh,
                          const float* __restrict__ pcls,
                          const float* __restrict__ anchors,
                          const int* __restrict__ topi,
                          float4* __restrict__ boxesws,
                          int* __restrict__ labelsws,
                          float* __restrict__ out)
{
    int t = blockIdx.x * blockDim.x + threadIdx.x;
    if (t >= B_N * K_N) return;
    int b = t / K_N;
    int a = topi[t];

    float4 tb = ((const float4*)ptxywh)[(size_t)b * A_N + a];
    float4 an = ((const float4*)anchors)[a];

    float xx = an.x + (tb.x * 0.1f) * an.z;
    float yy = an.y + (tb.y * 0.1f) * an.w;
    float ww = an.z * (float)exp((double)(tb.z * 0.2f));
    float hh = an.w * (float)exp((double)(tb.w * 0.2f));
    float hw = ww * 0.5f, hh2 = hh * 0.5f;
    boxesws[t] = make_float4(xx - hw, yy - hh2, xx + hw, yy + hh2);

    const float4* pc = (const float4*)(pcls + ((size_t)b * A_N + a) * C_N);
    float m = -INFINITY; int lab = 0;
#pragma unroll
    for (int q = 0; q < 5; ++q) {
        float4 v = pc[q];
        if (v.x > m) { m = v.x; lab = q * 4 + 0; }
        if (v.y > m) { m = v.y; lab = q * 4 + 1; }
        if (v.z > m) { m = v.z; lab = q * 4 + 2; }
        if (v.w > m) { m = v.w; lab = q * 4 + 3; }
    }
    labelsws[t] = lab + 1;

    out[t] = (float)b;                                 // ids_batch
    out[5 * B_N * K_N + t] = (float)(lab + 1);         // labels
}

// ---------------------------------------------------------------- kernel 4
// suppression bitmask: bit j of word w of row i <=> iou(i, w*64+j) > 0.5, j != i
__global__ void k4_mask(const float4* __restrict__ boxesws,
                        const int* __restrict__ labelsws,
                        unsigned long long* __restrict__ mask)
{
    const int b = blockIdx.y;
    const int tid = threadIdx.x;
    __shared__ float4 obox[K_N];
    __shared__ float oarea[K_N];

    for (int idx = tid; idx < K_N; idx += 256) {
        float4 bx = boxesws[(size_t)b * K_N + idx];
        float off = (float)labelsws[(size_t)b * K_N + idx] * 10.0f;
        float l = bx.x + off, t2 = bx.y + off, r = bx.z + off, bo = bx.w + off;
        obox[idx] = make_float4(l, t2, r, bo);
        oarea[idx] = (r - l) * (bo - t2);
    }
    __syncthreads();

    const int il = tid & 63;
    const int i = blockIdx.x * 64 + il;
    if (i >= K_N) return;
    float4 bi = obox[i];
    float ai = oarea[i];
#pragma unroll
    for (int p = 0; p < 4; ++p) {
        int w = (tid >> 6) + p * 4;
        unsigned long long word = 0ull;
        for (int jj = 0; jj < 64; ++jj) {
            int j = w * 64 + jj;
            if (j < K_N && j != i) {
                float4 bj = obox[j];
                float lx = fmaxf(bi.x, bj.x);
                float ly = fmaxf(bi.y, bj.y);
                float rx = fminf(bi.z, bj.z);
                float ry = fminf(bi.w, bj.w);
                float wx = fmaxf(rx - lx, 0.0f);
                float wy = fmaxf(ry - ly, 0.0f);
                float inter = wx * wy;
                float uni = ai + oarea[j] - inter;
                float den = fmaxf(uni, 1e-9f);
                float iou = inter / den;
                if (iou > 0.5f) word |= (1ull << jj);
            }
        }
        mask[((size_t)b * K_N + i) * 16 + w] = word;
    }
}

// ---------------------------------------------------------------- kernel 5
// greedy NMS scan, one block (1024 thr) per batch. Thread t owns mask row t
// in registers; wave c runs chunk c's serial scan; symmetric-IoU makes the
// cross-chunk suppression union a single AND per thread.
__global__ void __launch_bounds__(1024)
k5_scan(const unsigned long long* __restrict__ mask,
        const float* __restrict__ topv,
        const float4* __restrict__ boxesws,
        float* __restrict__ out)
{
    const int b = blockIdx.x;
    const int t = threadIdx.x;          // row id; rows >= K_N inactive
    const int lane = t & 63;
    const int wv = t >> 6;              // wave id == chunk id

    __shared__ unsigned long long intrarow[64];
    __shared__ unsigned long long keep_s;
    __shared__ unsigned long long keeparr[16];

    const bool inr = t < K_N;
    const float* tv = topv + (size_t)b * K_N;
    const bool valid = inr && (tv[inr ? t : 0] >= 0.5f);

    // my mask row (16 u64 words) in registers, coalesced-ish parallel load
    const unsigned long long* mrp = mask + ((size_t)b * K_N + (inr ? t : 0)) * 16;
    ulonglong2 mrow[8];
#pragma unroll
    for (int i = 0; i < 8; ++i) {
        ulonglong2 v = ((const ulonglong2*)mrp)[i];
        if (!inr) { v.x = 0ull; v.y = 0ull; }
        mrow[i] = v;
    }

    bool suppressed = false;

#pragma unroll
    for (int d = 0; d < 16; ++d) {
        const unsigned long long iw = (d & 1) ? mrow[d >> 1].y : mrow[d >> 1].x;
        if (wv == d) intrarow[lane] = iw;
        __syncthreads();
        if (wv == d) {
            unsigned long long validw = __ballot(valid && !suppressed);
            unsigned long long cw = 0ull, keepw = 0ull;
            for (int r = 0; r < 64; ++r) {
                bool kb = ((validw >> r) & 1ull) && !((cw >> r) & 1ull);
                unsigned long long sel = kb ? intrarow[r] : 0ull;
                cw |= sel;
                keepw |= (kb ? 1ull : 0ull) << r;
            }
            if (lane == 0) { keep_s = keepw; keeparr[d] = keepw; }
        }
        __syncthreads();
        if (iw & keep_s) suppressed = true;
    }

    __syncthreads();
    // outputs: boxes*keep, scores*keep, keep
    float* out_boxes  = out + (size_t)B_N * K_N;          // 32000
    float* out_scores = out + (size_t)6 * B_N * K_N;      // 192000
    float* out_keep   = out + (size_t)7 * B_N * K_N;      // 224000
    if (inr) {
        float kf = ((keeparr[wv] >> lane) & 1ull) ? 1.0f : 0.0f;
        float4 bx = boxesws[(size_t)b * K_N + t];
        size_t o = (size_t)b * K_N + t;
        out_boxes[o * 4 + 0] = bx.x * kf;
        out_boxes[o * 4 + 1] = bx.y * kf;
        out_boxes[o * 4 + 2] = bx.z * kf;
        out_boxes[o * 4 + 3] = bx.w * kf;
        out_scores[o] = tv[t] * kf;
        out_keep[o] = kf;
    }
}

// ---------------------------------------------------------------- launch
extern "C" void kernel_launch(void* const* d_in, const int* in_sizes, int n_in,
                              void* d_out, int out_size, void* d_ws, size_t ws_size,
                              hipStream_t stream)
{
    const float* ptxywh  = (const float*)d_in[0];
    const float* pcls    = (const float*)d_in[1];
    const float* anchors = (const float*)d_in[2];
    float* out = (float*)d_out;

    char* ws = (char*)d_ws;
    size_t o = 0;
    float* pscore = (float*)(ws + o);               o += (size_t)B_N * A_N * 4;
    int*   topi   = (int*)(ws + o);                 o += (size_t)B_N * K_N * 4;
    float* topv   = (float*)(ws + o);               o += (size_t)B_N * K_N * 4;
    float4* boxesws = (float4*)(ws + o);            o += (size_t)B_N * K_N * 16;
    int*   labelsws = (int*)(ws + o);               o += (size_t)B_N * K_N * 4;
    unsigned long long* mask = (unsigned long long*)(ws + o);
    o += (size_t)B_N * K_N * 16 * 8;

    int total = B_N * A_N;
    k1_score<<<(total + 255) / 256, 256, 0, stream>>>(pcls, pscore, total);
    k2_topk<<<B_N, 1024, 0, stream>>>(pscore, topi, topv);
    k3_decode<<<(B_N * K_N + 255) / 256, 256, 0, stream>>>(ptxywh, pcls, anchors,
                                                           topi, boxesws, labelsws, out);
    k4_mask<<<dim3(16, B_N), 256, 0, stream>>>(boxesws, labelsws, mask);
    k5_scan<<<B_N, 1024, 0, stream>>>(mask, topv, boxesws, out);
}